// Round 11
// baseline (2221.239 us; speedup 1.0000x reference)
//
#include <hip/hip_runtime.h>
#include <math.h>

using u16 = unsigned short;
using bf16x8 = __attribute__((ext_vector_type(8))) short;
using f32x4  = __attribute__((ext_vector_type(4))) float;

#define DEV static __device__ __forceinline__

DEV u16 f2bf(float f) {
  union { float f; unsigned u; } v; v.f = f;
  unsigned u = v.u + 0x7fffu + ((v.u >> 16) & 1u);
  return (u16)(u >> 16);
}

DEV void gload16(const void* g, void* l) {
  __builtin_amdgcn_global_load_lds(
      (const __attribute__((address_space(1))) void*)g,
      (__attribute__((address_space(3))) void*)l, 16, 0, 0);
}

// ---------------- prep kernels ----------------
__global__ void k_conv_bf16(const float* __restrict__ in, u16* __restrict__ out, int n) {
  int i = blockIdx.x * 256 + threadIdx.x;
  if (i < n) out[i] = f2bf(in[i]);
}

// in: f32 [K][Nin] row-major ; out: bf16 [Nout][K] (n-major).
// pack==1: n' = d2*48+j maps to n = d2*47+j for j<47, j==47 -> 0 (pad).
__global__ void k_transconv(const float* __restrict__ in, u16* __restrict__ out,
                            int K, int Nin, int Nout, int pack) {
  __shared__ float t[32][33];
  int kb = blockIdx.x * 32, nb = blockIdx.y * 32;
  int tx = threadIdx.x & 31, ty = threadIdx.x >> 5;  // 32 x 8
  #pragma unroll
  for (int i = 0; i < 4; ++i) {
    int k = kb + ty + i * 8;
    int no = nb + tx;
    float v = 0.f;
    if (k < K && no < Nout) {
      if (pack) {
        int r = no % 48;
        if (r < 47) v = in[(size_t)k * Nin + (no / 48) * 47 + r];
      } else {
        v = in[(size_t)k * Nin + no];
      }
    }
    t[ty + i * 8][tx] = v;
  }
  __syncthreads();
  #pragma unroll
  for (int i = 0; i < 4; ++i) {
    int no = nb + ty + i * 8;
    int k = kb + tx;
    if (no < Nout && k < K) out[(size_t)no * K + k] = f2bf(t[tx][ty + i * 8]);
  }
}

// ---------------- GEMM + ReLU (BM=128,BN=128,BK=32, 4 waves) for GEMM1/2 ----------------
__global__ __launch_bounds__(256)
void k_gemm_relu(const u16* __restrict__ A, const u16* __restrict__ Bt,
                 const float* __restrict__ bias, u16* __restrict__ C,
                 int N, int K) {
  constexpr int BM = 128, BN = 128, BK = 32;
  __shared__ __align__(16) u16 lds[(BM + BN) * BK];
  int tid = threadIdx.x, w = tid >> 6, lane = tid & 63;
  int bn = blockIdx.x, bm = blockIdx.y;
  int brow = bm * BM, bcol = bn * BN;
  int wm = w >> 1, wn = w & 1;
  int fr = lane & 15, fg = lane >> 4;
  f32x4 acc[4][4];
  #pragma unroll
  for (int i = 0; i < 4; ++i)
    #pragma unroll
    for (int j = 0; j < 4; ++j) acc[i][j] = (f32x4){0.f, 0.f, 0.f, 0.f};

  constexpr int ACH = BM * BK / 8;
  constexpr int CALLS = (BM + BN) * BK / 8 / 64;

  for (int kt = 0; kt < K; kt += BK) {
    for (int j = 0; j * 4 + w < CALLS; ++j) {
      int cb = (j * 4 + w) * 64;
      int c = cb + lane;
      const u16* g;
      if (c < ACH) {
        int row = c >> 2, c8 = c & 3;
        g = A + (size_t)(brow + row) * K + kt + c8 * 8;
      } else {
        int b = c - ACH;
        int nn = b >> 2, c8 = b & 3;
        g = Bt + (size_t)(bcol + nn) * K + kt + c8 * 8;
      }
      gload16(g, &lds[cb * 8]);
    }
    asm volatile("s_waitcnt vmcnt(0)" ::: "memory");
    __syncthreads();

    const u16* Al = lds;
    const u16* Bl = lds + BM * BK;
    bf16x8 af[4], bfr[4];
    #pragma unroll
    for (int mi = 0; mi < 4; ++mi)
      af[mi] = *(const bf16x8*)&Al[(wm * 64 + mi * 16 + fr) * BK + fg * 8];
    #pragma unroll
    for (int ni = 0; ni < 4; ++ni)
      bfr[ni] = *(const bf16x8*)&Bl[(wn * 64 + ni * 16 + fr) * BK + fg * 8];
    #pragma unroll
    for (int mi = 0; mi < 4; ++mi)
      #pragma unroll
      for (int ni = 0; ni < 4; ++ni)
        acc[mi][ni] = __builtin_amdgcn_mfma_f32_16x16x32_bf16(af[mi], bfr[ni], acc[mi][ni], 0, 0, 0);
    __syncthreads();
  }

  #pragma unroll
  for (int ni = 0; ni < 4; ++ni) {
    int col = bcol + wn * 64 + ni * 16 + fr;
    float bb = bias[col];
    #pragma unroll
    for (int mi = 0; mi < 4; ++mi) {
      #pragma unroll
      for (int q = 0; q < 4; ++q) {
        int row = brow + wm * 64 + mi * 16 + fg * 4 + q;
        float vv = acc[mi][ni][q] + bb;
        C[(size_t)row * N + col] = f2bf(vv > 0.f ? vv : 0.f);
      }
    }
  }
}

// ------- GEMM3 fused w/ spline: BM=256, BN=384, BK=32, 16 waves (1024 thr), 3-slot ring -------
// Traffic-minimal tile: per-block operands 1.25MB; chip traffic A(32x33.5MB)+B(64x25MB)
// = 2.68GB = 0.5x R7/R10 (delivery-capped at ~11.5 B/cyc/CU -> ~380us floor).
// LDS ring: 3 slots x 40960 (A [256][64B] + B [384][64B]); depth-2 prefetch; per-wave
// counted vmcnt (3 stage-instrs for waves 0-7, 2 for 8-15). 64B-row swizzle:
// chunk ^= (row>>1)&3 -- conflict-free per 8-lane phase group (verified covers 32 banks).
// Per wave (4wm x 4wn): 64x96 out, acc[4][6]=96 regs, 10 ds_read_b128 -> 24 MFMA/tile.
// __launch_bounds__(1024,4) pins regs <=128 -> 16 waves/CU resident.
__global__ __launch_bounds__(1024, 4)
void k_gemm3_fused(const u16* __restrict__ A, const u16* __restrict__ Bt,
                   const float* __restrict__ b2, const float* __restrict__ x2,
                   float* __restrict__ y2, float* __restrict__ ldpart) {
  extern __shared__ char smem[];
  const int tid = threadIdx.x, w = tid >> 6, lane = tid & 63;
  const int wm = w >> 2, wn = w & 3;
  const int fr = lane & 15, fg = lane >> 4;

  const int bid = blockIdx.x;                          // 2048 = 64 bm x 32 bn
  const int bm = bid >> 5;
  const int bn = ((bid & 7) << 2) | ((bid >> 3) & 3);  // XCD-chunked: 4 bn-panels/XCD = 3MB L2
  const int brow = bm * 256;

  // staging: thread -> (row = tid>>2, chunk c = tid&3); source chunk pre-XOR'd
  // csrc = c ^ ((row>>1)&3) = (tid&3) ^ ((tid>>3)&3); LDS dest linear tid*16 (rule #21)
  const int csrc = (tid & 3) ^ ((tid >> 3) & 3);
  const u16* gA  = A  + (size_t)(brow + (tid >> 2)) * 1024 + csrc * 8;          // rows 0-255
  const u16* gB1 = Bt + (size_t)(bn * 384 + (tid >> 2)) * 1024 + csrc * 8;      // rows 0-255
  const u16* gB2 = Bt + (size_t)(bn * 384 + 256 + (tid >> 2)) * 1024 + csrc * 8; // rows 256-383 (tid<512)

#define STAGE(t1, sb) {                                               \
    const size_t ko_ = (size_t)(t1) * 32;                             \
    char* p_ = smem + (sb);                                           \
    gload16(gA + ko_, p_ + tid * 16);                                 \
    gload16(gB1 + ko_, p_ + 16384 + tid * 16);                        \
    if (tid < 512) gload16(gB2 + ko_, p_ + 32768 + tid * 16); }

#define VMW_T() { if (w < 8) asm volatile("s_waitcnt vmcnt(3)" ::: "memory"); \
                  else       asm volatile("s_waitcnt vmcnt(2)" ::: "memory"); }
#define BARRIER() { __builtin_amdgcn_sched_barrier(0); __builtin_amdgcn_s_barrier(); \
                    __builtin_amdgcn_sched_barrier(0); }

  // swizzled read chunk offset: chunk = fg ^ ((row>>1)&3); row base mult of 16 -> (fr>>1)&3
  const int sc = ((fg ^ ((fr >> 1) & 3)) << 4);
  const int abase = (wm * 64 + fr) * 64 + sc;
  const int bbase = (wn * 96 + fr) * 64 + sc;

  f32x4 acc[4][6];
  #pragma unroll
  for (int m = 0; m < 4; ++m)
    #pragma unroll
    for (int n = 0; n < 6; ++n) acc[m][n] = (f32x4){0.f, 0.f, 0.f, 0.f};

#define COMPUTE(sb) {                                                 \
    const char* Ab_ = smem + (sb);                                    \
    const char* Bb_ = smem + (sb) + 16384;                            \
    bf16x8 a_[4];                                                     \
    _Pragma("unroll")                                                 \
    for (int m_ = 0; m_ < 4; ++m_)                                    \
      a_[m_] = *(const bf16x8*)(Ab_ + abase + m_ * 1024);             \
    __builtin_amdgcn_s_setprio(1);                                    \
    _Pragma("unroll")                                                 \
    for (int n_ = 0; n_ < 6; ++n_) {                                  \
      bf16x8 b_ = *(const bf16x8*)(Bb_ + bbase + n_ * 1024);          \
      _Pragma("unroll")                                               \
      for (int m_ = 0; m_ < 4; ++m_)                                  \
        acc[m_][n_] = __builtin_amdgcn_mfma_f32_16x16x32_bf16(a_[m_], b_, acc[m_][n_], 0, 0, 0); \
    }                                                                 \
    __builtin_amdgcn_s_setprio(0); }

  // prologue: fill slots 0,1 (tiles 0,1); wait tile 0 (leave tile 1 in flight)
  STAGE(0, 0); STAGE(1, 40960);
  VMW_T();
  BARRIER();

  // steady state: t = 0..29 (unroll 3 for static slot bases); stage t+2 at top
  for (int j = 0; j < 10; ++j) {
    STAGE(3 * j + 2, 81920); COMPUTE(0);     VMW_T(); BARRIER();
    STAGE(3 * j + 3, 0);     COMPUTE(40960); VMW_T(); BARRIER();
    STAGE(3 * j + 4, 40960); COMPUTE(81920); VMW_T(); BARRIER();
  }
  // tail: t=30 (slot 0), t=31 (slot 1); stages for 30,31 were issued at t=28,29
  COMPUTE(0);
  asm volatile("s_waitcnt vmcnt(0)" ::: "memory");
  BARRIER();
  COMPUTE(40960);
  __syncthreads();

  // ---- epilogue: 4 rounds (rh2 = row-half-of-256, pp = group-parity) ----
  // writers: waves with (wm>>1)==rh2 -> slot[wn] = [128][49] f32 (4 slots, 100352 B)
  float* fl = (float*)smem;
  float* ldacc = (float*)(smem + 100352);  // [256][8] f32
  #pragma unroll
  for (int r = 0; r < 4; ++r) {
    const int rh2 = r >> 1, pp = r & 1;
    if ((wm >> 1) == rh2) {
      float* slot = fl + wn * (128 * 49);
      #pragma unroll
      for (int m = 0; m < 4; ++m)
        #pragma unroll
        for (int j = 0; j < 3; ++j)
          #pragma unroll
          for (int q = 0; q < 4; ++q)
            slot[((wm & 1) * 64 + m * 16 + fg * 4 + q) * 49 + j * 16 + fr] = acc[m][pp * 3 + j][q];
    }
    __syncthreads();
    if (tid < 512) {
      const int g = tid >> 7, rr = tid & 127;
      const float* pr = fl + g * (128 * 49) + rr * 49;
      const int grow = brow + rh2 * 128 + rr;
      const int d2 = bn * 8 + g * 2 + pp;
      const float* bb = b2 + (size_t)d2 * 47;

      float wv[16], hv[16];
      #pragma unroll
      for (int j = 0; j < 16; ++j) wv[j] = pr[j] + bb[j];
      #pragma unroll
      for (int j = 0; j < 16; ++j) hv[j] = pr[16 + j] + bb[16 + j];

      float x = x2[(size_t)grow * 256 + d2];
      float xc = fminf(fmaxf(x, -3.f), 3.f);

      float mw = wv[0];
      #pragma unroll
      for (int j = 1; j < 16; ++j) mw = fmaxf(mw, wv[j]);
      float sw = 0.f;
      #pragma unroll
      for (int j = 0; j < 16; ++j) { wv[j] = __expf(wv[j] - mw); sw += wv[j]; }
      float scw = 0.984f / sw;

      float mh = hv[0];
      #pragma unroll
      for (int j = 1; j < 16; ++j) mh = fmaxf(mh, hv[j]);
      float sh = 0.f;
      #pragma unroll
      for (int j = 0; j < 16; ++j) { hv[j] = __expf(hv[j] - mh); sh += hv[j]; }
      float sch = 0.984f / sh;

      int idx = 0;
      float xk = -3.f, cum = 0.f;
      #pragma unroll
      for (int i = 1; i <= 15; ++i) {
        cum += 0.001f + wv[i - 1] * scw;
        float cwi = 6.f * cum - 3.f;
        if (xc >= cwi) { idx = i; xk = cwi; }
      }
      float yk = -3.f, cumh = 0.f;
      #pragma unroll
      for (int i = 1; i <= 15; ++i) {
        cumh += 0.001f + hv[i - 1] * sch;
        float chi = 6.f * cumh - 3.f;
        if (i == idx) yk = chi;
      }
      float wk = 1.f, hk = 1.f;
      #pragma unroll
      for (int i = 0; i < 16; ++i) {
        if (i == idx) {
          wk = 6.f * (0.001f + wv[i] * scw);
          hk = 6.f * (0.001f + hv[i] * sch);
        }
      }
      float dk = 1.f, dk1 = 1.f;
      #pragma unroll
      for (int i = 1; i <= 15; ++i) {
        float u = pr[32 + i - 1] + bb[32 + i - 1];
        float e = __expf(u);
        float dd = 0.001f + (u > 15.f ? u : log1pf(e));
        if (i == idx) dk = dd;
        if (i == idx + 1) dk1 = dd;
      }

      float sk = hk / wk;
      float th = (xc - xk) / wk;
      float om = 1.f - th;
      float t1m = th * om;
      float den = sk + (dk + dk1 - 2.f * sk) * t1m;
      float y = yk + hk * (sk * th * th + dk * t1m) / den;
      float deriv = sk * sk * (dk1 * th * th + 2.f * sk * t1m + dk * om * om) / (den * den);
      bool inside = (x > -3.f) && (x < 3.f);
      float yout = inside ? y : x;
      float ld = inside ? __logf(deriv) : 0.f;

      y2[(size_t)grow * 256 + d2] = yout;
      ldacc[(rh2 * 128 + rr) * 8 + g * 2 + pp] = ld;
    }
    __syncthreads();
  }

  if (tid < 256) {
    float s = 0.f;
    #pragma unroll
    for (int g = 0; g < 8; ++g) s += ldacc[tid * 8 + g];
    ldpart[(size_t)bn * 16384 + brow + tid] = s;
  }
}

__global__ void k_reduce_ld(const float* __restrict__ part, float* __restrict__ out) {
  int r = blockIdx.x * 256 + threadIdx.x;
  float s = 0.f;
  for (int j = 0; j < 32; ++j) s += part[(size_t)j * 16384 + r];
  out[r] = s;
}

// ---------------- launch ----------------
extern "C" void kernel_launch(void* const* d_in, const int* in_sizes, int n_in,
                              void* d_out, int out_size, void* d_ws, size_t ws_size,
                              hipStream_t stream) {
  const float* x1 = (const float*)d_in[0];
  const float* x2 = (const float*)d_in[1];
  const float* W0 = (const float*)d_in[2];
  const float* b0 = (const float*)d_in[3];
  const float* W1 = (const float*)d_in[4];
  const float* b1 = (const float*)d_in[5];
  const float* W2 = (const float*)d_in[6];
  const float* b2 = (const float*)d_in[7];
  float* y2 = (float*)d_out;
  float* logdet = y2 + (size_t)16384 * 256;

  char* ws = (char*)d_ws;
  u16* W2t = (u16*)ws;                                   // 25165824
  u16* W0t = (u16*)(ws + 25165824);                      //   524288
  u16* W1t = (u16*)(ws + 25165824 + 524288);             //  2097152
  u16* x1b = (u16*)(ws + 27787264);                      //  8388608
  float* ldp = (float*)(ws + 27787264);                  // aliases x1b (dead by GEMM3); 32*16384*4=2MB
  u16* h1  = (u16*)(ws + 36175872);                      // 33554432
  u16* h2  = (u16*)(ws + 69730304);                      // 33554432

  hipFuncSetAttribute((const void*)k_gemm3_fused,
                      hipFuncAttributeMaxDynamicSharedMemorySize, 122880);

  k_conv_bf16<<<16384, 256, 0, stream>>>(x1, x1b, 16384 * 256);
  k_transconv<<<dim3(8, 32), 256, 0, stream>>>(W0, W0t, 256, 1024, 1024, 0);
  k_transconv<<<dim3(32, 32), 256, 0, stream>>>(W1, W1t, 1024, 1024, 1024, 0);
  k_transconv<<<dim3(32, 384), 256, 0, stream>>>(W2, W2t, 1024, 12032, 12288, 1);

  k_gemm_relu<<<dim3(8, 128), 256, 0, stream>>>(x1b, W0t, b0, h1, 1024, 256);
  k_gemm_relu<<<dim3(8, 128), 256, 0, stream>>>(h1, W1t, b1, h2, 1024, 1024);
  k_gemm3_fused<<<2048, 1024, 122880, stream>>>(h2, W2t, b2, x2, y2, ldp);
  k_reduce_ld<<<64, 256, 0, stream>>>(ldp, logdet);
}

// Round 13
// 747.332 us; speedup vs baseline: 2.9722x; 2.9722x over previous
//
#include <hip/hip_runtime.h>
#include <math.h>

using u16 = unsigned short;
using bf16x8 = __attribute__((ext_vector_type(8))) short;
using f32x4  = __attribute__((ext_vector_type(4))) float;

#define DEV static __device__ __forceinline__

DEV u16 f2bf(float f) {
  union { float f; unsigned u; } v; v.f = f;
  unsigned u = v.u + 0x7fffu + ((v.u >> 16) & 1u);
  return (u16)(u >> 16);
}

DEV void gload16(const void* g, void* l) {
  __builtin_amdgcn_global_load_lds(
      (const __attribute__((address_space(1))) void*)g,
      (__attribute__((address_space(3))) void*)l, 16, 0, 0);
}

// ---------------- prep kernels ----------------
__global__ void k_conv_bf16(const float* __restrict__ in, u16* __restrict__ out, int n) {
  int i = blockIdx.x * 256 + threadIdx.x;
  if (i < n) out[i] = f2bf(in[i]);
}

// in: f32 [K][Nin] row-major ; out: bf16 [Nout][K] (n-major).
// pack==1: n' = d2*48+j maps to n = d2*47+j for j<47, j==47 -> 0 (pad).
__global__ void k_transconv(const float* __restrict__ in, u16* __restrict__ out,
                            int K, int Nin, int Nout, int pack) {
  __shared__ float t[32][33];
  int kb = blockIdx.x * 32, nb = blockIdx.y * 32;
  int tx = threadIdx.x & 31, ty = threadIdx.x >> 5;  // 32 x 8
  #pragma unroll
  for (int i = 0; i < 4; ++i) {
    int k = kb + ty + i * 8;
    int no = nb + tx;
    float v = 0.f;
    if (k < K && no < Nout) {
      if (pack) {
        int r = no % 48;
        if (r < 47) v = in[(size_t)k * Nin + (no / 48) * 47 + r];
      } else {
        v = in[(size_t)k * Nin + no];
      }
    }
    t[ty + i * 8][tx] = v;
  }
  __syncthreads();
  #pragma unroll
  for (int i = 0; i < 4; ++i) {
    int no = nb + ty + i * 8;
    int k = kb + tx;
    if (no < Nout && k < K) out[(size_t)no * K + k] = f2bf(t[tx][ty + i * 8]);
  }
}

// ---------------- GEMM + ReLU (BM=128,BN=128,BK=32, 4 waves) for GEMM1/2 ----------------
__global__ __launch_bounds__(256)
void k_gemm_relu(const u16* __restrict__ A, const u16* __restrict__ Bt,
                 const float* __restrict__ bias, u16* __restrict__ C,
                 int N, int K) {
  constexpr int BM = 128, BN = 128, BK = 32;
  __shared__ __align__(16) u16 lds[(BM + BN) * BK];
  int tid = threadIdx.x, w = tid >> 6, lane = tid & 63;
  int bn = blockIdx.x, bm = blockIdx.y;
  int brow = bm * BM, bcol = bn * BN;
  int wm = w >> 1, wn = w & 1;
  int fr = lane & 15, fg = lane >> 4;
  f32x4 acc[4][4];
  #pragma unroll
  for (int i = 0; i < 4; ++i)
    #pragma unroll
    for (int j = 0; j < 4; ++j) acc[i][j] = (f32x4){0.f, 0.f, 0.f, 0.f};

  constexpr int ACH = BM * BK / 8;
  constexpr int CALLS = (BM + BN) * BK / 8 / 64;

  for (int kt = 0; kt < K; kt += BK) {
    for (int j = 0; j * 4 + w < CALLS; ++j) {
      int cb = (j * 4 + w) * 64;
      int c = cb + lane;
      const u16* g;
      if (c < ACH) {
        int row = c >> 2, c8 = c & 3;
        g = A + (size_t)(brow + row) * K + kt + c8 * 8;
      } else {
        int b = c - ACH;
        int nn = b >> 2, c8 = b & 3;
        g = Bt + (size_t)(bcol + nn) * K + kt + c8 * 8;
      }
      gload16(g, &lds[cb * 8]);
    }
    asm volatile("s_waitcnt vmcnt(0)" ::: "memory");
    __syncthreads();

    const u16* Al = lds;
    const u16* Bl = lds + BM * BK;
    bf16x8 af[4], bfr[4];
    #pragma unroll
    for (int mi = 0; mi < 4; ++mi)
      af[mi] = *(const bf16x8*)&Al[(wm * 64 + mi * 16 + fr) * BK + fg * 8];
    #pragma unroll
    for (int ni = 0; ni < 4; ++ni)
      bfr[ni] = *(const bf16x8*)&Bl[(wn * 64 + ni * 16 + fr) * BK + fg * 8];
    #pragma unroll
    for (int mi = 0; mi < 4; ++mi)
      #pragma unroll
      for (int ni = 0; ni < 4; ++ni)
        acc[mi][ni] = __builtin_amdgcn_mfma_f32_16x16x32_bf16(af[mi], bfr[ni], acc[mi][ni], 0, 0, 0);
    __syncthreads();
  }

  #pragma unroll
  for (int ni = 0; ni < 4; ++ni) {
    int col = bcol + wn * 64 + ni * 16 + fr;
    float bb = bias[col];
    #pragma unroll
    for (int mi = 0; mi < 4; ++mi) {
      #pragma unroll
      for (int q = 0; q < 4; ++q) {
        int row = brow + wm * 64 + mi * 16 + fg * 4 + q;
        float vv = acc[mi][ni][q] + bb;
        C[(size_t)row * N + col] = f2bf(vv > 0.f ? vv : 0.f);
      }
    }
  }
}

// ------- GEMM3 fused with spline: BM=128, BN=192, BK=32, 4 waves, 3 BLOCKS/CU -------
// R7's proven kernel with BK 64->32 (LDS dbuf 2x20480; request 52224 ->
// floor(163840/52224)=3 blocks/CU = 12 waves, the m97/R1 overlap regime).
// K=1024 / BK=32 = 32 tiles (R12's 64-tile overrun was the correctness bug).
// 64-B-row swizzle (R11-verified): stage csrc = (tid&3)^((tid>>3)&3), read
// chunk = fg ^ ((fr>>1)&3). Per tile: 5 DMA/thread; 10 ds_read_b128 -> 24 MFMA/wave.
__global__ __launch_bounds__(256, 3)
void k_gemm3_fused(const u16* __restrict__ A, const u16* __restrict__ Bt,
                   const float* __restrict__ b2, const float* __restrict__ x2,
                   float* __restrict__ y2, float* __restrict__ ldpart) {
  extern __shared__ char smem[];
  const int tid = threadIdx.x, w = tid >> 6, lane = tid & 63;
  const int wm = w >> 1, wn = w & 1;
  const int fr = lane & 15, fg = lane >> 4;

  const int bid = blockIdx.x;                     // 8192 blocks
  const int bm = bid >> 6;                        // 0..127
  const int bn = ((bid & 7) << 3) | ((bid >> 3) & 7);  // 0..63, XCD-chunked
  const int brow = bm * 128;

  // staging: row = tid>>2 (+64k per unit), chunk c = tid&3 of the 64B row.
  // source chunk pre-XOR'd: csrc = c ^ ((row>>1)&3); row+64k keeps (row>>1)&3.
  // LDS dest linear tid*16 + unit*4096 (rule #21).
  const int csrc = (tid & 3) ^ ((tid >> 3) & 3);
  const u16* gA0 = A + (size_t)(brow + (tid >> 2)) * 1024 + csrc * 8;
  const u16* gB0 = Bt + (size_t)(bn * 192 + (tid >> 2)) * 1024 + csrc * 8;

#define ISSUE_ALL(t1) {                                               \
    const size_t ko_ = (size_t)(t1) * 32;                             \
    char* p_ = smem + ((t1) & 1) * 20480 + tid * 16;                  \
    gload16(gA0 + ko_, p_);                                           \
    gload16(gA0 + 65536 + ko_, p_ + 4096);                            \
    gload16(gB0 + ko_, p_ + 8192);                                    \
    gload16(gB0 + 65536 + ko_, p_ + 12288);                           \
    gload16(gB0 + 131072 + ko_, p_ + 16384); }

  // swizzled read chunk offset (bytes): chunk = fg ^ ((row>>1)&3), (row>>1)&3 == (fr>>1)&3
  const int sc = ((fg ^ ((fr >> 1) & 3)) << 4);

  f32x4 acc[4][6];
  #pragma unroll
  for (int m = 0; m < 4; ++m)
    #pragma unroll
    for (int n = 0; n < 6; ++n) acc[m][n] = (f32x4){0.f, 0.f, 0.f, 0.f};

  ISSUE_ALL(0);
  asm volatile("s_waitcnt vmcnt(0)" ::: "memory");
  __syncthreads();

  for (int t = 0; t < 32; ++t) {
    if (t < 31) ISSUE_ALL(t + 1);
    const char* Ab = smem + (t & 1) * 20480;
    const char* Bb = Ab + 8192;
    bf16x8 b[6];
    #pragma unroll
    for (int n = 0; n < 6; ++n)
      b[n] = *(const bf16x8*)(Bb + (wn * 96 + n * 16 + fr) * 64 + sc);
    __builtin_amdgcn_s_setprio(1);
    #pragma unroll
    for (int m = 0; m < 4; ++m) {
      bf16x8 a = *(const bf16x8*)(Ab + (wm * 64 + m * 16 + fr) * 64 + sc);
      #pragma unroll
      for (int n = 0; n < 6; ++n)
        acc[m][n] = __builtin_amdgcn_mfma_f32_16x16x32_bf16(a, b[n], acc[m][n], 0, 0, 0);
    }
    __builtin_amdgcn_s_setprio(0);
    asm volatile("s_waitcnt vmcnt(0)" ::: "memory");
    __syncthreads();
  }

  // ---- epilogue (R7-proven): 2 row-half rounds; 4 slots [64][49] f32 ----
  float* ldacc = (float*)(smem + 50176);  // [128][4]
  float* fl = (float*)smem;
  #pragma unroll
  for (int rh = 0; rh < 2; ++rh) {
    if (wm == rh) {
      #pragma unroll
      for (int m = 0; m < 4; ++m)
        #pragma unroll
        for (int n = 0; n < 6; ++n) {
          const int g = wn * 2 + (n >= 3 ? 1 : 0);
          const int ci = (n % 3) * 16 + fr;
          #pragma unroll
          for (int q = 0; q < 4; ++q)
            fl[g * 3136 + (m * 16 + fg * 4 + q) * 49 + ci] = acc[m][n][q];
        }
    }
    __syncthreads();
    {
      const int g = tid >> 6, r = tid & 63;
      const float* pr = fl + g * 3136 + r * 49;
      const int grow = brow + rh * 64 + r;
      const int d2 = bn * 4 + g;
      const float* bb = b2 + (size_t)d2 * 47;

      float wv[16], hv[16];
      #pragma unroll
      for (int j = 0; j < 16; ++j) wv[j] = pr[j] + bb[j];
      #pragma unroll
      for (int j = 0; j < 16; ++j) hv[j] = pr[16 + j] + bb[16 + j];

      float x = x2[(size_t)grow * 256 + d2];
      float xc = fminf(fmaxf(x, -3.f), 3.f);

      float mw = wv[0];
      #pragma unroll
      for (int j = 1; j < 16; ++j) mw = fmaxf(mw, wv[j]);
      float sw = 0.f;
      #pragma unroll
      for (int j = 0; j < 16; ++j) { wv[j] = __expf(wv[j] - mw); sw += wv[j]; }
      float scw = 0.984f / sw;

      float mh = hv[0];
      #pragma unroll
      for (int j = 1; j < 16; ++j) mh = fmaxf(mh, hv[j]);
      float sh = 0.f;
      #pragma unroll
      for (int j = 0; j < 16; ++j) { hv[j] = __expf(hv[j] - mh); sh += hv[j]; }
      float sch = 0.984f / sh;

      int idx = 0;
      float xk = -3.f, cum = 0.f;
      #pragma unroll
      for (int i = 1; i <= 15; ++i) {
        cum += 0.001f + wv[i - 1] * scw;
        float cwi = 6.f * cum - 3.f;
        if (xc >= cwi) { idx = i; xk = cwi; }
      }
      float yk = -3.f, cumh = 0.f;
      #pragma unroll
      for (int i = 1; i <= 15; ++i) {
        cumh += 0.001f + hv[i - 1] * sch;
        float chi = 6.f * cumh - 3.f;
        if (i == idx) yk = chi;
      }
      float wk = 1.f, hk = 1.f;
      #pragma unroll
      for (int i = 0; i < 16; ++i) {
        if (i == idx) {
          wk = 6.f * (0.001f + wv[i] * scw);
          hk = 6.f * (0.001f + hv[i] * sch);
        }
      }
      float dk = 1.f, dk1 = 1.f;
      #pragma unroll
      for (int i = 1; i <= 15; ++i) {
        float u = pr[32 + i - 1] + bb[32 + i - 1];
        float e = __expf(u);
        float dd = 0.001f + (u > 15.f ? u : log1pf(e));
        if (i == idx) dk = dd;
        if (i == idx + 1) dk1 = dd;
      }

      float sk = hk / wk;
      float th = (xc - xk) / wk;
      float om = 1.f - th;
      float t1m = th * om;
      float den = sk + (dk + dk1 - 2.f * sk) * t1m;
      float y = yk + hk * (sk * th * th + dk * t1m) / den;
      float deriv = sk * sk * (dk1 * th * th + 2.f * sk * t1m + dk * om * om) / (den * den);
      bool inside = (x > -3.f) && (x < 3.f);
      float yout = inside ? y : x;
      float ld = inside ? __logf(deriv) : 0.f;

      y2[(size_t)grow * 256 + d2] = yout;
      ldacc[(rh * 64 + r) * 4 + g] = ld;
    }
    __syncthreads();
  }

  if (tid < 128) {
    float s = ldacc[tid * 4] + ldacc[tid * 4 + 1] + ldacc[tid * 4 + 2] + ldacc[tid * 4 + 3];
    ldpart[(size_t)bn * 16384 + brow + tid] = s;
  }
}

__global__ void k_reduce_ld(const float* __restrict__ part, float* __restrict__ out) {
  int r = blockIdx.x * 256 + threadIdx.x;
  float s = 0.f;
  for (int j = 0; j < 64; ++j) s += part[(size_t)j * 16384 + r];
  out[r] = s;
}

// ---------------- launch ----------------
extern "C" void kernel_launch(void* const* d_in, const int* in_sizes, int n_in,
                              void* d_out, int out_size, void* d_ws, size_t ws_size,
                              hipStream_t stream) {
  const float* x1 = (const float*)d_in[0];
  const float* x2 = (const float*)d_in[1];
  const float* W0 = (const float*)d_in[2];
  const float* b0 = (const float*)d_in[3];
  const float* W1 = (const float*)d_in[4];
  const float* b1 = (const float*)d_in[5];
  const float* W2 = (const float*)d_in[6];
  const float* b2 = (const float*)d_in[7];
  float* y2 = (float*)d_out;
  float* logdet = y2 + (size_t)16384 * 256;

  char* ws = (char*)d_ws;
  u16* W2t = (u16*)ws;                                   // 25165824
  u16* W0t = (u16*)(ws + 25165824);                      //   524288
  u16* W1t = (u16*)(ws + 25165824 + 524288);             //  2097152
  u16* x1b = (u16*)(ws + 27787264);                      //  8388608
  float* ldp = (float*)(ws + 27787264);                  // aliases x1b (dead by GEMM3); 64*16384*4=4MB
  u16* h1  = (u16*)(ws + 36175872);                      // 33554432
  u16* h2  = (u16*)(ws + 69730304);                      // 33554432

  hipFuncSetAttribute((const void*)k_gemm3_fused,
                      hipFuncAttributeMaxDynamicSharedMemorySize, 52224);

  k_conv_bf16<<<16384, 256, 0, stream>>>(x1, x1b, 16384 * 256);
  k_transconv<<<dim3(8, 32), 256, 0, stream>>>(W0, W0t, 256, 1024, 1024, 0);
  k_transconv<<<dim3(32, 32), 256, 0, stream>>>(W1, W1t, 1024, 1024, 1024, 0);
  k_transconv<<<dim3(32, 384), 256, 0, stream>>>(W2, W2t, 1024, 12032, 12288, 1);

  k_gemm_relu<<<dim3(8, 128), 256, 0, stream>>>(x1b, W0t, b0, h1, 1024, 256);
  k_gemm_relu<<<dim3(8, 128), 256, 0, stream>>>(h1, W1t, b1, h2, 1024, 1024);
  k_gemm3_fused<<<8192, 256, 52224, stream>>>(h2, W2t, b2, x2, y2, ldp);
  k_reduce_ld<<<64, 256, 0, stream>>>(ldp, logdet);
}

// Round 14
// 708.609 us; speedup vs baseline: 3.1346x; 1.0546x over previous
//
#include <hip/hip_runtime.h>
#include <math.h>

using u16 = unsigned short;
using bf16x8 = __attribute__((ext_vector_type(8))) short;
using f32x4  = __attribute__((ext_vector_type(4))) float;

#define DEV static __device__ __forceinline__

DEV u16 f2bf(float f) {
  union { float f; unsigned u; } v; v.f = f;
  unsigned u = v.u + 0x7fffu + ((v.u >> 16) & 1u);
  return (u16)(u >> 16);
}

DEV void gload16(const void* g, void* l) {
  __builtin_amdgcn_global_load_lds(
      (const __attribute__((address_space(1))) void*)g,
      (__attribute__((address_space(3))) void*)l, 16, 0, 0);
}

// ---------------- prep kernels ----------------
__global__ void k_conv_bf16(const float* __restrict__ in, u16* __restrict__ out, int n) {
  int i = blockIdx.x * 256 + threadIdx.x;
  if (i < n) out[i] = f2bf(in[i]);
}

// in: f32 [K][Nin] row-major ; out: bf16 [Nout][K] (n-major).
// pack==1: n' = d2*48+j maps to n = d2*47+j for j<47, j==47 -> 0 (pad).
__global__ void k_transconv(const float* __restrict__ in, u16* __restrict__ out,
                            int K, int Nin, int Nout, int pack) {
  __shared__ float t[32][33];
  int kb = blockIdx.x * 32, nb = blockIdx.y * 32;
  int tx = threadIdx.x & 31, ty = threadIdx.x >> 5;  // 32 x 8
  #pragma unroll
  for (int i = 0; i < 4; ++i) {
    int k = kb + ty + i * 8;
    int no = nb + tx;
    float v = 0.f;
    if (k < K && no < Nout) {
      if (pack) {
        int r = no % 48;
        if (r < 47) v = in[(size_t)k * Nin + (no / 48) * 47 + r];
      } else {
        v = in[(size_t)k * Nin + no];
      }
    }
    t[ty + i * 8][tx] = v;
  }
  __syncthreads();
  #pragma unroll
  for (int i = 0; i < 4; ++i) {
    int no = nb + ty + i * 8;
    int k = kb + tx;
    if (no < Nout && k < K) out[(size_t)no * K + k] = f2bf(t[tx][ty + i * 8]);
  }
}

// ---------------- GEMM + ReLU (BM=128,BN=128,BK=32, 4 waves) for GEMM1/2 ----------------
__global__ __launch_bounds__(256)
void k_gemm_relu(const u16* __restrict__ A, const u16* __restrict__ Bt,
                 const float* __restrict__ bias, u16* __restrict__ C,
                 int N, int K) {
  constexpr int BM = 128, BN = 128, BK = 32;
  __shared__ __align__(16) u16 lds[(BM + BN) * BK];
  int tid = threadIdx.x, w = tid >> 6, lane = tid & 63;
  int bn = blockIdx.x, bm = blockIdx.y;
  int brow = bm * BM, bcol = bn * BN;
  int wm = w >> 1, wn = w & 1;
  int fr = lane & 15, fg = lane >> 4;
  f32x4 acc[4][4];
  #pragma unroll
  for (int i = 0; i < 4; ++i)
    #pragma unroll
    for (int j = 0; j < 4; ++j) acc[i][j] = (f32x4){0.f, 0.f, 0.f, 0.f};

  constexpr int ACH = BM * BK / 8;
  constexpr int CALLS = (BM + BN) * BK / 8 / 64;

  for (int kt = 0; kt < K; kt += BK) {
    for (int j = 0; j * 4 + w < CALLS; ++j) {
      int cb = (j * 4 + w) * 64;
      int c = cb + lane;
      const u16* g;
      if (c < ACH) {
        int row = c >> 2, c8 = c & 3;
        g = A + (size_t)(brow + row) * K + kt + c8 * 8;
      } else {
        int b = c - ACH;
        int nn = b >> 2, c8 = b & 3;
        g = Bt + (size_t)(bcol + nn) * K + kt + c8 * 8;
      }
      gload16(g, &lds[cb * 8]);
    }
    asm volatile("s_waitcnt vmcnt(0)" ::: "memory");
    __syncthreads();

    const u16* Al = lds;
    const u16* Bl = lds + BM * BK;
    bf16x8 af[4], bfr[4];
    #pragma unroll
    for (int mi = 0; mi < 4; ++mi)
      af[mi] = *(const bf16x8*)&Al[(wm * 64 + mi * 16 + fr) * BK + fg * 8];
    #pragma unroll
    for (int ni = 0; ni < 4; ++ni)
      bfr[ni] = *(const bf16x8*)&Bl[(wn * 64 + ni * 16 + fr) * BK + fg * 8];
    #pragma unroll
    for (int mi = 0; mi < 4; ++mi)
      #pragma unroll
      for (int ni = 0; ni < 4; ++ni)
        acc[mi][ni] = __builtin_amdgcn_mfma_f32_16x16x32_bf16(af[mi], bfr[ni], acc[mi][ni], 0, 0, 0);
    __syncthreads();
  }

  #pragma unroll
  for (int ni = 0; ni < 4; ++ni) {
    int col = bcol + wn * 64 + ni * 16 + fr;
    float bb = bias[col];
    #pragma unroll
    for (int mi = 0; mi < 4; ++mi) {
      #pragma unroll
      for (int q = 0; q < 4; ++q) {
        int row = brow + wm * 64 + mi * 16 + fg * 4 + q;
        float vv = acc[mi][ni][q] + bb;
        C[(size_t)row * N + col] = f2bf(vv > 0.f ? vv : 0.f);
      }
    }
  }
}

// ------- GEMM3 fused with spline: BM=128, BN=192, BK=32, 4 waves, DEPTH-2 RING, 2 blk/CU -------
// R13's verified kernel (tile, swizzle, XCD map, epilogue, 32 tiles) with the loop upgraded
// to a 3-slot LDS ring (3 x 20480 = 61440 B -> 2 blocks/CU):
//   top of tile t:  STAGE(t+2) into slot (t+2)%3   [slot was last read in tile t-1, done]
//   end of tile t:  s_waitcnt vmcnt(5)  [retires tile t+1's 5 loads, issued at top of t-1
//                   -> 2-tile (~1200+ cyc) lead >= LLC miss latency] + RAW s_barrier
//                   (NOT __syncthreads: that drains vmcnt(0) and kills the pipeline).
// Uniform 5 gload16/thread/STAGE keeps the per-wave vmcnt ledger exact.
__global__ __launch_bounds__(256, 2)
void k_gemm3_fused(const u16* __restrict__ A, const u16* __restrict__ Bt,
                   const float* __restrict__ b2, const float* __restrict__ x2,
                   float* __restrict__ y2, float* __restrict__ ldpart) {
  extern __shared__ char smem[];
  const int tid = threadIdx.x, w = tid >> 6, lane = tid & 63;
  const int wm = w >> 1, wn = w & 1;
  const int fr = lane & 15, fg = lane >> 4;

  const int bid = blockIdx.x;                     // 8192 blocks
  const int bm = bid >> 6;                        // 0..127
  const int bn = ((bid & 7) << 3) | ((bid >> 3) & 7);  // 0..63, XCD-chunked
  const int brow = bm * 128;

  // staging: row = tid>>2 (+64k per unit), chunk c = tid&3 of the 64B row.
  // source chunk pre-XOR'd: csrc = c ^ ((row>>1)&3); LDS dest linear (rule #21).
  const int csrc = (tid & 3) ^ ((tid >> 3) & 3);
  const u16* gA0 = A + (size_t)(brow + (tid >> 2)) * 1024 + csrc * 8;
  const u16* gB0 = Bt + (size_t)(bn * 192 + (tid >> 2)) * 1024 + csrc * 8;

#define STAGE(t1, sb) {                                               \
    const size_t ko_ = (size_t)(t1) * 32;                             \
    char* p_ = smem + (sb) + tid * 16;                                \
    gload16(gA0 + ko_, p_);                                           \
    gload16(gA0 + 65536 + ko_, p_ + 4096);                            \
    gload16(gB0 + ko_, p_ + 8192);                                    \
    gload16(gB0 + 65536 + ko_, p_ + 12288);                           \
    gload16(gB0 + 131072 + ko_, p_ + 16384); }

  // swizzled read chunk offset (bytes): chunk = fg ^ ((fr>>1)&3)
  const int sc = ((fg ^ ((fr >> 1) & 3)) << 4);

  f32x4 acc[4][6];
  #pragma unroll
  for (int m = 0; m < 4; ++m)
    #pragma unroll
    for (int n = 0; n < 6; ++n) acc[m][n] = (f32x4){0.f, 0.f, 0.f, 0.f};

#define COMPUTE(sb) {                                                 \
    const char* Ab_ = smem + (sb);                                    \
    const char* Bb_ = Ab_ + 8192;                                     \
    bf16x8 b_[6];                                                     \
    _Pragma("unroll")                                                 \
    for (int n_ = 0; n_ < 6; ++n_)                                    \
      b_[n_] = *(const bf16x8*)(Bb_ + (wn * 96 + n_ * 16 + fr) * 64 + sc); \
    __builtin_amdgcn_s_setprio(1);                                    \
    _Pragma("unroll")                                                 \
    for (int m_ = 0; m_ < 4; ++m_) {                                  \
      bf16x8 a_ = *(const bf16x8*)(Ab_ + (wm * 64 + m_ * 16 + fr) * 64 + sc); \
      _Pragma("unroll")                                               \
      for (int n_ = 0; n_ < 6; ++n_)                                  \
        acc[m_][n_] = __builtin_amdgcn_mfma_f32_16x16x32_bf16(a_, b_[n_], acc[m_][n_], 0, 0, 0); \
    }                                                                 \
    __builtin_amdgcn_s_setprio(0); }

#define VMW(n) { asm volatile("s_waitcnt vmcnt(" #n ")" ::: "memory"); \
                 __builtin_amdgcn_sched_barrier(0); }
#define RBAR() { __builtin_amdgcn_s_barrier(); __builtin_amdgcn_sched_barrier(0); }

  // prologue: stage tiles 0,1; wait tile 0 (tile 1's 5 stay in flight)
  STAGE(0, 0); STAGE(1, 20480);
  VMW(5);
  RBAR();

  // t = 0..29 (unrolled by 3 for static slot bases); stage t+2 at top of t
  for (int j = 0; j < 10; ++j) {
    STAGE(3 * j + 2, 40960); COMPUTE(0);     VMW(5); RBAR();
    STAGE(3 * j + 3, 0);     COMPUTE(20480); VMW(5); RBAR();
    STAGE(3 * j + 4, 20480); COMPUTE(40960); VMW(5); RBAR();
  }
  // tail: t=30 (slot 0; tile 31's 5 outstanding), t=31 (slot 1)
  COMPUTE(0); VMW(0); RBAR();
  COMPUTE(20480);
  __syncthreads();

  // ---- epilogue (R7/R13-proven): 2 row-half rounds; 4 slots [64][49] f32 ----
  float* ldacc = (float*)(smem + 50176);  // [128][4]
  float* fl = (float*)smem;
  #pragma unroll
  for (int rh = 0; rh < 2; ++rh) {
    if (wm == rh) {
      #pragma unroll
      for (int m = 0; m < 4; ++m)
        #pragma unroll
        for (int n = 0; n < 6; ++n) {
          const int g = wn * 2 + (n >= 3 ? 1 : 0);
          const int ci = (n % 3) * 16 + fr;
          #pragma unroll
          for (int q = 0; q < 4; ++q)
            fl[g * 3136 + (m * 16 + fg * 4 + q) * 49 + ci] = acc[m][n][q];
        }
    }
    __syncthreads();
    {
      const int g = tid >> 6, r = tid & 63;
      const float* pr = fl + g * 3136 + r * 49;
      const int grow = brow + rh * 64 + r;
      const int d2 = bn * 4 + g;
      const float* bb = b2 + (size_t)d2 * 47;

      float wv[16], hv[16];
      #pragma unroll
      for (int j = 0; j < 16; ++j) wv[j] = pr[j] + bb[j];
      #pragma unroll
      for (int j = 0; j < 16; ++j) hv[j] = pr[16 + j] + bb[16 + j];

      float x = x2[(size_t)grow * 256 + d2];
      float xc = fminf(fmaxf(x, -3.f), 3.f);

      float mw = wv[0];
      #pragma unroll
      for (int j = 1; j < 16; ++j) mw = fmaxf(mw, wv[j]);
      float sw = 0.f;
      #pragma unroll
      for (int j = 0; j < 16; ++j) { wv[j] = __expf(wv[j] - mw); sw += wv[j]; }
      float scw = 0.984f / sw;

      float mh = hv[0];
      #pragma unroll
      for (int j = 1; j < 16; ++j) mh = fmaxf(mh, hv[j]);
      float sh = 0.f;
      #pragma unroll
      for (int j = 0; j < 16; ++j) { hv[j] = __expf(hv[j] - mh); sh += hv[j]; }
      float sch = 0.984f / sh;

      int idx = 0;
      float xk = -3.f, cum = 0.f;
      #pragma unroll
      for (int i = 1; i <= 15; ++i) {
        cum += 0.001f + wv[i - 1] * scw;
        float cwi = 6.f * cum - 3.f;
        if (xc >= cwi) { idx = i; xk = cwi; }
      }
      float yk = -3.f, cumh = 0.f;
      #pragma unroll
      for (int i = 1; i <= 15; ++i) {
        cumh += 0.001f + hv[i - 1] * sch;
        float chi = 6.f * cumh - 3.f;
        if (i == idx) yk = chi;
      }
      float wk = 1.f, hk = 1.f;
      #pragma unroll
      for (int i = 0; i < 16; ++i) {
        if (i == idx) {
          wk = 6.f * (0.001f + wv[i] * scw);
          hk = 6.f * (0.001f + hv[i] * sch);
        }
      }
      float dk = 1.f, dk1 = 1.f;
      #pragma unroll
      for (int i = 1; i <= 15; ++i) {
        float u = pr[32 + i - 1] + bb[32 + i - 1];
        float e = __expf(u);
        float dd = 0.001f + (u > 15.f ? u : log1pf(e));
        if (i == idx) dk = dd;
        if (i == idx + 1) dk1 = dd;
      }

      float sk = hk / wk;
      float th = (xc - xk) / wk;
      float om = 1.f - th;
      float t1m = th * om;
      float den = sk + (dk + dk1 - 2.f * sk) * t1m;
      float y = yk + hk * (sk * th * th + dk * t1m) / den;
      float deriv = sk * sk * (dk1 * th * th + 2.f * sk * t1m + dk * om * om) / (den * den);
      bool inside = (x > -3.f) && (x < 3.f);
      float yout = inside ? y : x;
      float ld = inside ? __logf(deriv) : 0.f;

      y2[(size_t)grow * 256 + d2] = yout;
      ldacc[(rh * 64 + r) * 4 + g] = ld;
    }
    __syncthreads();
  }

  if (tid < 128) {
    float s = ldacc[tid * 4] + ldacc[tid * 4 + 1] + ldacc[tid * 4 + 2] + ldacc[tid * 4 + 3];
    ldpart[(size_t)bn * 16384 + brow + tid] = s;
  }
}

__global__ void k_reduce_ld(const float* __restrict__ part, float* __restrict__ out) {
  int r = blockIdx.x * 256 + threadIdx.x;
  float s = 0.f;
  for (int j = 0; j < 64; ++j) s += part[(size_t)j * 16384 + r];
  out[r] = s;
}

// ---------------- launch ----------------
extern "C" void kernel_launch(void* const* d_in, const int* in_sizes, int n_in,
                              void* d_out, int out_size, void* d_ws, size_t ws_size,
                              hipStream_t stream) {
  const float* x1 = (const float*)d_in[0];
  const float* x2 = (const float*)d_in[1];
  const float* W0 = (const float*)d_in[2];
  const float* b0 = (const float*)d_in[3];
  const float* W1 = (const float*)d_in[4];
  const float* b1 = (const float*)d_in[5];
  const float* W2 = (const float*)d_in[6];
  const float* b2 = (const float*)d_in[7];
  float* y2 = (float*)d_out;
  float* logdet = y2 + (size_t)16384 * 256;

  char* ws = (char*)d_ws;
  u16* W2t = (u16*)ws;                                   // 25165824
  u16* W0t = (u16*)(ws + 25165824);                      //   524288
  u16* W1t = (u16*)(ws + 25165824 + 524288);             //  2097152
  u16* x1b = (u16*)(ws + 27787264);                      //  8388608
  float* ldp = (float*)(ws + 27787264);                  // aliases x1b (dead by GEMM3); 64*16384*4=4MB
  u16* h1  = (u16*)(ws + 36175872);                      // 33554432
  u16* h2  = (u16*)(ws + 69730304);                      // 33554432

  hipFuncSetAttribute((const void*)k_gemm3_fused,
                      hipFuncAttributeMaxDynamicSharedMemorySize, 61440);

  k_conv_bf16<<<16384, 256, 0, stream>>>(x1, x1b, 16384 * 256);
  k_transconv<<<dim3(8, 32), 256, 0, stream>>>(W0, W0t, 256, 1024, 1024, 0);
  k_transconv<<<dim3(32, 32), 256, 0, stream>>>(W1, W1t, 1024, 1024, 1024, 0);
  k_transconv<<<dim3(32, 384), 256, 0, stream>>>(W2, W2t, 1024, 12032, 12288, 1);

  k_gemm_relu<<<dim3(8, 128), 256, 0, stream>>>(x1b, W0t, b0, h1, 1024, 256);
  k_gemm_relu<<<dim3(8, 128), 256, 0, stream>>>(h1, W1t, b1, h2, 1024, 1024);
  k_gemm3_fused<<<8192, 256, 61440, stream>>>(h2, W2t, b2, x2, y2, ldp);
  k_reduce_ld<<<64, 256, 0, stream>>>(ldp, logdet);
}